// Round 11
// baseline (477.011 us; speedup 1.0000x reference)
//
#include <hip/hip_runtime.h>
#include <math.h>

// Problem constants (B=1)
#define MM 1024
#define DD 512
#define CC 128

// ws layout (floats):
//  H2[1024][2048]     @ 0         (cols 0..1023 ms-hidden fp32, 1024.. src_proj fp32)
//  antb bf16[1024][1024] @ 2097152
//  slow[1024][128]    @ 2621440
//  spk_proj[2][1024]  @ 2752512
//  bkt_proj[10][1024] @ 2754560
//  ms[1024]           @ 2764800
//  lossp[1024]        @ 2765824
//  embb bf16[1024][512]  @ 2766848
//  Wall bf16[4096][512]  @ 3028992
//    rows [0,1024)=ms_W0^T, [1024,2048)=W_src^T, [2048,3072)=W_ant^T
//    tail 1MB = Wfrag3: [chunk:16][s:32][t:2][lane:64][8] bf16
//      element (f = chunk*64 + t*32 + (lane&31), k = s*16 + (lane>>5)*8 + j)

typedef __attribute__((ext_vector_type(8))) short bf16x8;
typedef __attribute__((ext_vector_type(4))) float f32x4;
typedef __attribute__((ext_vector_type(16))) float f32x16;

__device__ __forceinline__ ushort bf16_rn(float x) {
    uint u = __float_as_uint(x);
    uint r = u + 0x7fffu + ((u >> 16) & 1u);
    return (ushort)(r >> 16);
}
__device__ __forceinline__ float bf16_to_f(ushort u) {
    return __uint_as_float(((uint)u) << 16);
}

// ---------------- prep: emb fp32 -> bf16
__global__ __launch_bounds__(256) void prep_emb(const float* __restrict__ emb,
                                                ushort* __restrict__ embb)
{
    int i = blockIdx.x * 256 + threadIdx.x;
    float2 v = ((const float2*)emb)[i];
    ushort2 o;
    o.x = bf16_rn(v.x);
    o.y = bf16_rn(v.y);
    ((ushort2*)embb)[i] = o;
}

// ---------------- prep: transpose+convert W0 blocks -> Wall[3072 n][512 k] bf16
__global__ __launch_bounds__(256) void prep_wall(const float* __restrict__ ms_W0,
                                                 const float* __restrict__ sp_W0,
                                                 ushort* __restrict__ Wall)
{
    __shared__ float t[64][65];
    const int k0 = blockIdx.x * 64;   // 8
    const int n0 = blockIdx.y * 64;   // 48
    const int g = n0 >> 10;
    const float* src = (g == 0) ? ms_W0 : (sp_W0 + (size_t)(g - 1) * 512 * 1024);
    const int col0 = n0 & 1023;
    const int tr = threadIdx.x >> 6, tc = threadIdx.x & 63;
#pragma unroll
    for (int i = 0; i < 16; ++i) {
        int k = tr + i * 4;
        t[k][tc] = src[(size_t)(k0 + k) * 1024 + col0 + tc];
    }
    __syncthreads();
    const int f = threadIdx.x >> 2;
    const int c4 = threadIdx.x & 3;
    ushort tmp[16];
#pragma unroll
    for (int j = 0; j < 16; ++j) tmp[j] = bf16_rn(t[c4 * 16 + j][f]);
    uint4* dst = (uint4*)(Wall + (size_t)(n0 + f) * 512 + k0 + c4 * 16);
    dst[0] = *(uint4*)&tmp[0];
    dst[1] = *(uint4*)&tmp[8];
}

// ---------------- prep: W_prod -> Wfrag3 [chunk:16][s:32][t:2][lane:64][8]
__global__ __launch_bounds__(128) void prep_wfrag3(const float* __restrict__ sp_W0,
                                                   ushort* __restrict__ Wfrag3)
{
    const int chunk = blockIdx.x;        // 0..15
    const int s = blockIdx.y;            // 0..31
    const int t = threadIdx.x >> 6;      // 0..1
    const int l = threadIdx.x & 63;
    const int f = chunk * 64 + t * 32 + (l & 31);
    const int kb = s * 16 + (l >> 5) * 8;
    const float* W = sp_W0 + (size_t)1024 * 1024;   // W_prod [k=512][f=1024]
    ushort tmp[8];
#pragma unroll
    for (int j = 0; j < 8; ++j) tmp[j] = bf16_rn(W[(size_t)(kb + j) * 1024 + f]);
    uint4* dst = (uint4*)(Wfrag3 + ((((size_t)chunk * 32 + s) * 2 + t) * 64 + l) * 8);
    *dst = *(uint4*)&tmp[0];
}

// ---------------- H2/antb = emb @ [ms_W0 | W_src | W_ant] via MFMA
__global__ __launch_bounds__(256) void gemm_h_mfma(
    const ushort* __restrict__ embb, const ushort* __restrict__ Wall,
    float* __restrict__ H2, ushort* __restrict__ antb)
{
    const int n0 = blockIdx.x * 128;  // 24
    const int m0 = blockIdx.y * 128;  // 8
    const int lane = threadIdx.x & 63, wave = threadIdx.x >> 6;
    const int wx = wave & 1, wy = wave >> 1;
    const int l15 = lane & 15, lq = lane >> 4;

    const ushort* arow[4];
#pragma unroll
    for (int mi = 0; mi < 4; ++mi)
        arow[mi] = embb + (size_t)(m0 + wy * 64 + mi * 16 + l15) * 512;
    const ushort* brow[4];
#pragma unroll
    for (int ni = 0; ni < 4; ++ni)
        brow[ni] = Wall + (size_t)(n0 + wx * 64 + ni * 16 + l15) * 512;

    f32x4 acc[4][4];
#pragma unroll
    for (int i = 0; i < 4; ++i)
#pragma unroll
        for (int j = 0; j < 4; ++j) acc[i][j] = (f32x4)0.f;

    for (int kt = 0; kt < 512; kt += 32) {
        const int ko = kt + lq * 8;
        bf16x8 av[4], bv[4];
#pragma unroll
        for (int mi = 0; mi < 4; ++mi) av[mi] = *(const bf16x8*)(arow[mi] + ko);
#pragma unroll
        for (int ni = 0; ni < 4; ++ni) bv[ni] = *(const bf16x8*)(brow[ni] + ko);
#pragma unroll
        for (int mi = 0; mi < 4; ++mi)
#pragma unroll
            for (int ni = 0; ni < 4; ++ni)
                acc[mi][ni] = __builtin_amdgcn_mfma_f32_16x16x32_bf16(av[mi], bv[ni], acc[mi][ni], 0, 0, 0);
    }
    if (n0 < 2048) {
#pragma unroll
        for (int mi = 0; mi < 4; ++mi)
#pragma unroll
            for (int r = 0; r < 4; ++r) {
                int mrow = m0 + wy * 64 + mi * 16 + lq * 4 + r;
#pragma unroll
                for (int ni = 0; ni < 4; ++ni)
                    H2[(size_t)mrow * 2048 + n0 + wx * 64 + ni * 16 + l15] = acc[mi][ni][r];
            }
    } else {
#pragma unroll
        for (int mi = 0; mi < 4; ++mi)
#pragma unroll
            for (int r = 0; r < 4; ++r) {
                int mrow = m0 + wy * 64 + mi * 16 + lq * 4 + r;
#pragma unroll
                for (int ni = 0; ni < 4; ++ni)
                    antb[(size_t)mrow * 1024 + (n0 - 2048) + wx * 64 + ni * 16 + l15] =
                        bf16_rn(acc[mi][ni][r]);
            }
    }
}

// ---------------- small projections
__global__ void small_proj(const float* __restrict__ speaker_emb,
                           const float* __restrict__ bucket_emb,
                           const float* __restrict__ sp_W0,
                           float* __restrict__ spk_proj, float* __restrict__ bkt_proj)
{
    int r = blockIdx.x; // 0..11
    const float* e; const float* W; float* out;
    if (r < 2) { e = speaker_emb + r * 20; W = sp_W0 + (size_t)1536 * 1024; out = spk_proj + r * 1024; }
    else       { e = bucket_emb + (r - 2) * 20; W = sp_W0 + (size_t)1556 * 1024; out = bkt_proj + (r - 2) * 1024; }
    float ek[20];
#pragma unroll
    for (int k = 0; k < 20; ++k) ek[k] = e[k];
    for (int f = threadIdx.x; f < 1024; f += blockDim.x) {
        float s = 0.f;
#pragma unroll
        for (int k = 0; k < 20; ++k) s = fmaf(ek[k], W[(size_t)k * 1024 + f], s);
        out[f] = s;
    }
}

// ---------------- mention scores
__global__ __launch_bounds__(256) void mention_score(
    const float* __restrict__ H2, const float* __restrict__ ms_b0,
    const float* __restrict__ ms_W1, const float* __restrict__ ms_b1,
    float* __restrict__ ms)
{
    int m = blockIdx.x;
    float v = 0.f;
    for (int f = threadIdx.x; f < 1024; f += 256) {
        float h = H2[(size_t)m * 2048 + f] + ms_b0[f];
        v += fmaxf(h, 0.f) * ms_W1[f];
    }
#pragma unroll
    for (int o = 1; o < 64; o <<= 1) v += __shfl_xor(v, o);
    __shared__ float sm[4];
    if ((threadIdx.x & 63) == 0) sm[threadIdx.x >> 6] = v;
    __syncthreads();
    if (threadIdx.x == 0) ms[m] = sm[0] + sm[1] + sm[2] + sm[3] + ms_b1[0];
}

// ---------------- pair scorer v4b: block = (c-half, m), 512 thr = 8 waves, 2 blocks/CU.
// wave-tile = 32c x 64f, 4 passes; acc = 2 x f32x16 = 32 AGPR; ring a[2]+b[2][2] = 24
// arch regs -> combined ~80 of 128 budget (launch_bounds 512,4): no spill possible.
// A fragment-major in LDS (1 ds_read_b128 per 2 MFMA, imm offsets); B fragment-major
// in Wfrag3 (2 contiguous global b128 per step via 1 pointer + 1024B imm, +2KB bump).
__global__ __launch_bounds__(512, 4) void pair_mfma(
    const ushort* __restrict__ embb, const ushort* __restrict__ Wfrag3,
    const float* __restrict__ H2, const ushort* __restrict__ antb,
    const float* __restrict__ spk_proj, const float* __restrict__ bkt_proj,
    const float* __restrict__ sp_b0, const float* __restrict__ sp_W1,
    const int* __restrict__ speaker, float* __restrict__ slow)
{
    extern __shared__ ushort Afrag[];            // [ct:2][s:32][slot:64][8] = 32768 ushorts
    float* red = (float*)(Afrag + 32768);        // 4 pass * 8 wave * 32 = 1024 floats
    int* meta_ss = (int*)(red + 1024);           // 64
    int* meta_bk = meta_ss + 64;                 // 64
    const int ch = blockIdx.x;                   // c-half: 0 or 1
    const int m = blockIdx.y;
    const int tid = threadIdx.x;
    const int spk_m = speaker[m];

    // ---- build A fragments: A[c][k] = bf16(em[k]*ea[k]); fragment-major store
    {
        const int c = tid >> 3;                  // 0..63 block-local
        const int q = tid & 7;                   // k chunk q*64
        const int cg = ch * 64 + c;
        int a = m - 1 - cg; if (a < 0) a = 0;
        const ushort* ea = embb + (size_t)a * 512 + q * 64;
        const ushort* em = embb + (size_t)m * 512 + q * 64;
        const int ct = c >> 5, c31 = c & 31;
#pragma unroll
        for (int j0 = 0; j0 < 64; j0 += 8) {
            bf16x8 va = *(const bf16x8*)(ea + j0);
            bf16x8 vm = *(const bf16x8*)(em + j0);
            uint pr[4];
#pragma unroll
            for (int p = 0; p < 4; ++p) {
                float q0 = bf16_to_f((ushort)va[2 * p])     * bf16_to_f((ushort)vm[2 * p]);
                float q1 = bf16_to_f((ushort)va[2 * p + 1]) * bf16_to_f((ushort)vm[2 * p + 1]);
                pr[p] = __builtin_amdgcn_perm(__float_as_uint(q1), __float_as_uint(q0), 0x07060302u);
            }
            const int s = q * 4 + (j0 >> 4);
            const int h = (j0 >> 3) & 1;
            ((uint4*)Afrag)[(ct * 32 + s) * 64 + h * 32 + c31] = *(uint4*)pr;
        }
        if (tid < 64) {
            const int cc = tid, cgg = ch * 64 + cc;
            int aa = m - 1 - cgg; if (aa < 0) aa = 0;
            meta_ss[cc] = (speaker[aa] == spk_m) ? 1 : 0;
            int off = cgg + 1;
            int bk;
            if (off <= 4) bk = off;
            else { bk = 31 - __clz(off) + 3; if (bk > 9) bk = 9; }
            meta_bk[cc] = bk;
        }
    }
    __syncthreads();

    const int lane = tid & 63;
    const int wave = __builtin_amdgcn_readfirstlane(tid >> 6);   // 0..7
    const int wc = wave & 1;          // c-tile within block
    const int wf = wave >> 1;         // f-group 0..3
    const int l31 = lane & 31, k5 = lane >> 5;

    // A base: lane slot fixed; step s at immediate offset s*1024 B
    const ushort* ap = Afrag + ((size_t)wc * 2048 + lane) * 8;

    for (int pass = 0; pass < 4; ++pass) {
        const int chunk = pass * 4 + wf;         // 64-f chunk
        const ushort* P = Wfrag3 + (size_t)chunk * 32768 + (size_t)lane * 8;

        f32x16 acc0 = (f32x16)0.f, acc1 = (f32x16)0.f;
        bf16x8 a[2], b[2][2];

        a[0] = *(const bf16x8*)(ap);
        a[1] = *(const bf16x8*)(ap + 512);
        b[0][0] = *(const bf16x8*)(P);
        b[0][1] = *(const bf16x8*)(P + 512);
        b[1][0] = *(const bf16x8*)(P + 1024);
        b[1][1] = *(const bf16x8*)(P + 1536);
        P += 2048;

#pragma unroll
        for (int s = 0; s < 32; ++s) {
            const int cur = s & 1;
            acc0 = __builtin_amdgcn_mfma_f32_32x32x16_bf16(a[cur], b[cur][0], acc0, 0, 0, 0);
            acc1 = __builtin_amdgcn_mfma_f32_32x32x16_bf16(a[cur], b[cur][1], acc1, 0, 0, 0);
            // prefetch s+2 (s=30,31 wrap into valid-but-unused ws/LDS bytes)
            a[cur] = *(const bf16x8*)(ap + (s + 2) * 512);
            b[cur][0] = *(const bf16x8*)(P);
            b[cur][1] = *(const bf16x8*)(P + 512);
            P += 1024;
        }

        // ---- epilogue for this pass (f-chunk chunk*64..+63)
        const int fb = chunk * 64 + l31;
        float srcb[2], w1v[2], sp0v[2], sp1v[2];
#pragma unroll
        for (int t = 0; t < 2; ++t) {
            const int fcol = fb + t * 32;
            srcb[t] = H2[(size_t)m * 2048 + 1024 + fcol] + sp_b0[fcol];
            w1v[t]  = sp_W1[fcol];
            sp0v[t] = spk_proj[fcol];
            sp1v[t] = spk_proj[1024 + fcol];
        }
#pragma unroll
        for (int reg = 0; reg < 16; ++reg) {
            const int row = 4 * k5 + (reg & 3) + 8 * (reg >> 2);
            const int c = wc * 32 + row;
            const int cg = ch * 64 + c;
            int a2 = m - 1 - cg; if (a2 < 0) a2 = 0;
            const int ss2 = meta_ss[c];
            const int bk = meta_bk[c];
            const ushort* antp = antb + (size_t)a2 * 1024;
            const float* bkp = bkt_proj + (size_t)bk * 1024;
            float av2[2] = { acc0[reg], acc1[reg] };
            float s = 0.f;
#pragma unroll
            for (int t = 0; t < 2; ++t) {
                const int fcol = fb + t * 32;
                float pre = av2[t] + srcb[t] + bf16_to_f(antp[fcol])
                          + (ss2 ? sp1v[t] : sp0v[t]) + bkp[fcol];
                s += fmaxf(pre, 0.f) * w1v[t];
            }
            s += __shfl_xor(s, 1); s += __shfl_xor(s, 2); s += __shfl_xor(s, 4);
            s += __shfl_xor(s, 8); s += __shfl_xor(s, 16);
            if (l31 == 0) red[pass * 256 + wave * 32 + row] = s;
        }
    }
    __syncthreads();
    if (tid < 64) {
        const int c = tid, row = c & 31, wcc = c >> 5;
        float s = 0.f;
#pragma unroll
        for (int pass = 0; pass < 4; ++pass)
#pragma unroll
            for (int wff = 0; wff < 4; ++wff)
                s += red[pass * 256 + (wff * 2 + wcc) * 32 + row];
        slow[(size_t)m * 128 + ch * 64 + c] = s;
    }
}

// ---------------- softmax + per-mention loss
__device__ __forceinline__ float bsum2(float v, float* sm) {
#pragma unroll
    for (int o = 1; o < 64; o <<= 1) v += __shfl_xor(v, o);
    __syncthreads();
    if ((threadIdx.x & 63) == 0) sm[threadIdx.x >> 6] = v;
    __syncthreads();
    return sm[0] + sm[1];
}
__device__ __forceinline__ float bmax2(float v, float* sm) {
#pragma unroll
    for (int o = 1; o < 64; o <<= 1) v = fmaxf(v, __shfl_xor(v, o));
    __syncthreads();
    if ((threadIdx.x & 63) == 0) sm[threadIdx.x >> 6] = v;
    __syncthreads();
    return fmaxf(sm[0], sm[1]);
}

__global__ __launch_bounds__(128) void softmax_loss(
    const float* __restrict__ slow, const float* __restrict__ ms,
    const float* __restrict__ sp_b1, const int* __restrict__ cluster,
    float* __restrict__ out, float* __restrict__ loss_partial)
{
    const int m = blockIdx.x, c = threadIdx.x;
    __shared__ float sm[2];
    const int raw = m - 1 - c;
    const bool maskv = raw >= 0;
    const int a = maskv ? raw : 0;
    float score = slow[(size_t)m * 128 + c] + sp_b1[0] + ms[m] + ms[a];
    if (!maskv) score = -INFINITY;

    float mx = fmaxf(bmax2(score, sm), 0.f);
    float e = expf(score - mx);
    float e0 = expf(0.f - mx);
    float sum = bsum2(e, sm) + e0;
    float p = e / sum, p0 = e0 / sum;
    const float eps = 1e-6f;
    p  = fminf(fmaxf(p,  eps), 1.f - eps);
    p0 = fminf(fmaxf(p0, eps), 1.f - eps);
    float sum2 = bsum2(p, sm) + p0;
    p /= sum2; p0 /= sum2;
    out[(size_t)m * 129 + 1 + c] = p;
    if (c == 0) out[(size_t)m * 129] = p0;

    const int cid = cluster[m];
    const bool lbl = maskv && (cid > 0) && (cluster[a] == cid);
    float anyc = bsum2(lbl ? 1.f : 0.f, sm);
    float lsum = bsum2(lbl ? -logf(p) : 0.f, sm);
    if (c == 0) {
        if (anyc == 0.f) lsum += -logf(p0);
        loss_partial[m] = lsum;
    }
}

__global__ void loss_sum(const float* __restrict__ lp, float* __restrict__ out) {
    float v = 0.f;
    for (int i = threadIdx.x; i < 1024; i += 256) v += lp[i];
#pragma unroll
    for (int o = 1; o < 64; o <<= 1) v += __shfl_xor(v, o);
    __shared__ float sm[4];
    if ((threadIdx.x & 63) == 0) sm[threadIdx.x >> 6] = v;
    __syncthreads();
    if (threadIdx.x == 0) out[(size_t)1024 * 129] = sm[0] + sm[1] + sm[2] + sm[3];
}

extern "C" void kernel_launch(void* const* d_in, const int* in_sizes, int n_in,
                              void* d_out, int out_size, void* d_ws, size_t ws_size,
                              hipStream_t stream)
{
    const float* emb   = (const float*)d_in[0];
    const int*   clus  = (const int*)  d_in[1];
    const int*   spk   = (const int*)  d_in[2];
    const float* ms_W0 = (const float*)d_in[3];
    const float* ms_b0 = (const float*)d_in[4];
    const float* ms_W1 = (const float*)d_in[5];
    const float* ms_b1 = (const float*)d_in[6];
    const float* sp_W0 = (const float*)d_in[7];
    const float* sp_b0 = (const float*)d_in[8];
    const float* sp_W1 = (const float*)d_in[9];
    const float* sp_b1 = (const float*)d_in[10];
    const float* spke  = (const float*)d_in[11];
    const float* bkte  = (const float*)d_in[12];

    float* ws = (float*)d_ws;
    float*  H2       = ws;
    ushort* antb     = (ushort*)(ws + 2097152);
    float*  slow     = ws + 2621440;
    float*  spk_proj = ws + 2752512;
    float*  bkt_proj = ws + 2754560;
    float*  msc      = ws + 2764800;
    float*  lossp    = ws + 2765824;
    ushort* embb     = (ushort*)(ws + 2766848);
    ushort* Wall     = (ushort*)(ws + 3028992);
    ushort* Wfrag3   = Wall + (size_t)3072 * 512;   // 1MB tail of Wall region
    float* out = (float*)d_out;

    const int pair_lds = 32768 * 2 + 1024 * 4 + 128 * 4;   // Afrag + red + meta = 70144 B

    static bool attr_set = false;
    if (!attr_set) {
        hipFuncSetAttribute((const void*)pair_mfma,
                            hipFuncAttributeMaxDynamicSharedMemorySize,
                            pair_lds);
        attr_set = true;
    }

    hipLaunchKernelGGL(prep_emb, dim3(1024), dim3(256), 0, stream, emb, embb);
    hipLaunchKernelGGL(prep_wall, dim3(8, 48), dim3(256), 0, stream, ms_W0, sp_W0, Wall);
    hipLaunchKernelGGL(prep_wfrag3, dim3(16, 32), dim3(128), 0, stream, sp_W0, Wfrag3);
    hipLaunchKernelGGL(gemm_h_mfma, dim3(24, 8), dim3(256), 0, stream, embb, Wall, H2, antb);
    hipLaunchKernelGGL(small_proj, dim3(12), dim3(256), 0, stream, spke, bkte, sp_W0, spk_proj, bkt_proj);
    hipLaunchKernelGGL(mention_score, dim3(1024), dim3(256), 0, stream, H2, ms_b0, ms_W1, ms_b1, msc);
    hipLaunchKernelGGL(pair_mfma, dim3(2, 1024), dim3(512), pair_lds, stream,
                       embb, Wfrag3, H2, antb, spk_proj, bkt_proj, sp_b0, sp_W1, spk, slow);
    hipLaunchKernelGGL(softmax_loss, dim3(1024), dim3(128), 0, stream,
                       slow, msc, sp_b1, clus, out, lossp);
    hipLaunchKernelGGL(loss_sum, dim3(1), dim3(256), 0, stream, lossp, out);
}

// Round 12
// 399.398 us; speedup vs baseline: 1.1943x; 1.1943x over previous
//
#include <hip/hip_runtime.h>
#include <math.h>

// Problem constants (B=1)
#define MM 1024
#define DD 512
#define CC 128

// ws layout (floats):
//  H2[1024][2048]     @ 0         (cols 0..1023 ms-hidden fp32, 1024.. src_proj fp32)
//  antb bf16[1024][1024] @ 2097152
//  slow[1024][128]    @ 2621440
//  spk_proj[2][1024]  @ 2752512
//  bkt_proj[10][1024] @ 2754560
//  ms[1024]           @ 2764800
//  lossp[1024]        @ 2765824
//  embb bf16[1024][512]  @ 2766848
//  Wall bf16[4096][512]  @ 3028992
//    rows [0,1024)=ms_W0^T, [1024,2048)=W_src^T, [2048,3072)=W_ant^T
//    tail 1MB = Wfrag3: [chunk:16][s:32][t:2][lane:64][8] bf16
//      element (f = chunk*64 + t*32 + (lane&31), k = s*16 + (lane>>5)*8 + j)

typedef __attribute__((ext_vector_type(8))) short bf16x8;
typedef __attribute__((ext_vector_type(4))) float f32x4;
typedef __attribute__((ext_vector_type(16))) float f32x16;

__device__ __forceinline__ ushort bf16_rn(float x) {
    uint u = __float_as_uint(x);
    uint r = u + 0x7fffu + ((u >> 16) & 1u);
    return (ushort)(r >> 16);
}
__device__ __forceinline__ float bf16_to_f(ushort u) {
    return __uint_as_float(((uint)u) << 16);
}

// ---------------- prep: emb fp32 -> bf16
__global__ __launch_bounds__(256) void prep_emb(const float* __restrict__ emb,
                                                ushort* __restrict__ embb)
{
    int i = blockIdx.x * 256 + threadIdx.x;
    float2 v = ((const float2*)emb)[i];
    ushort2 o;
    o.x = bf16_rn(v.x);
    o.y = bf16_rn(v.y);
    ((ushort2*)embb)[i] = o;
}

// ---------------- prep: transpose+convert W0 blocks -> Wall[3072 n][512 k] bf16
__global__ __launch_bounds__(256) void prep_wall(const float* __restrict__ ms_W0,
                                                 const float* __restrict__ sp_W0,
                                                 ushort* __restrict__ Wall)
{
    __shared__ float t[64][65];
    const int k0 = blockIdx.x * 64;   // 8
    const int n0 = blockIdx.y * 64;   // 48
    const int g = n0 >> 10;
    const float* src = (g == 0) ? ms_W0 : (sp_W0 + (size_t)(g - 1) * 512 * 1024);
    const int col0 = n0 & 1023;
    const int tr = threadIdx.x >> 6, tc = threadIdx.x & 63;
#pragma unroll
    for (int i = 0; i < 16; ++i) {
        int k = tr + i * 4;
        t[k][tc] = src[(size_t)(k0 + k) * 1024 + col0 + tc];
    }
    __syncthreads();
    const int f = threadIdx.x >> 2;
    const int c4 = threadIdx.x & 3;
    ushort tmp[16];
#pragma unroll
    for (int j = 0; j < 16; ++j) tmp[j] = bf16_rn(t[c4 * 16 + j][f]);
    uint4* dst = (uint4*)(Wall + (size_t)(n0 + f) * 512 + k0 + c4 * 16);
    dst[0] = *(uint4*)&tmp[0];
    dst[1] = *(uint4*)&tmp[8];
}

// ---------------- prep: W_prod -> Wfrag3 [chunk:16][s:32][t:2][lane:64][8]
__global__ __launch_bounds__(128) void prep_wfrag3(const float* __restrict__ sp_W0,
                                                   ushort* __restrict__ Wfrag3)
{
    const int chunk = blockIdx.x;        // 0..15
    const int s = blockIdx.y;            // 0..31
    const int t = threadIdx.x >> 6;      // 0..1
    const int l = threadIdx.x & 63;
    const int f = chunk * 64 + t * 32 + (l & 31);
    const int kb = s * 16 + (l >> 5) * 8;
    const float* W = sp_W0 + (size_t)1024 * 1024;   // W_prod [k=512][f=1024]
    ushort tmp[8];
#pragma unroll
    for (int j = 0; j < 8; ++j) tmp[j] = bf16_rn(W[(size_t)(kb + j) * 1024 + f]);
    uint4* dst = (uint4*)(Wfrag3 + ((((size_t)chunk * 32 + s) * 2 + t) * 64 + l) * 8);
    *dst = *(uint4*)&tmp[0];
}

// ---------------- H2/antb = emb @ [ms_W0 | W_src | W_ant] via MFMA
__global__ __launch_bounds__(256) void gemm_h_mfma(
    const ushort* __restrict__ embb, const ushort* __restrict__ Wall,
    float* __restrict__ H2, ushort* __restrict__ antb)
{
    const int n0 = blockIdx.x * 128;  // 24
    const int m0 = blockIdx.y * 128;  // 8
    const int lane = threadIdx.x & 63, wave = threadIdx.x >> 6;
    const int wx = wave & 1, wy = wave >> 1;
    const int l15 = lane & 15, lq = lane >> 4;

    const ushort* arow[4];
#pragma unroll
    for (int mi = 0; mi < 4; ++mi)
        arow[mi] = embb + (size_t)(m0 + wy * 64 + mi * 16 + l15) * 512;
    const ushort* brow[4];
#pragma unroll
    for (int ni = 0; ni < 4; ++ni)
        brow[ni] = Wall + (size_t)(n0 + wx * 64 + ni * 16 + l15) * 512;

    f32x4 acc[4][4];
#pragma unroll
    for (int i = 0; i < 4; ++i)
#pragma unroll
        for (int j = 0; j < 4; ++j) acc[i][j] = (f32x4)0.f;

    for (int kt = 0; kt < 512; kt += 32) {
        const int ko = kt + lq * 8;
        bf16x8 av[4], bv[4];
#pragma unroll
        for (int mi = 0; mi < 4; ++mi) av[mi] = *(const bf16x8*)(arow[mi] + ko);
#pragma unroll
        for (int ni = 0; ni < 4; ++ni) bv[ni] = *(const bf16x8*)(brow[ni] + ko);
#pragma unroll
        for (int mi = 0; mi < 4; ++mi)
#pragma unroll
            for (int ni = 0; ni < 4; ++ni)
                acc[mi][ni] = __builtin_amdgcn_mfma_f32_16x16x32_bf16(av[mi], bv[ni], acc[mi][ni], 0, 0, 0);
    }
    if (n0 < 2048) {
#pragma unroll
        for (int mi = 0; mi < 4; ++mi)
#pragma unroll
            for (int r = 0; r < 4; ++r) {
                int mrow = m0 + wy * 64 + mi * 16 + lq * 4 + r;
#pragma unroll
                for (int ni = 0; ni < 4; ++ni)
                    H2[(size_t)mrow * 2048 + n0 + wx * 64 + ni * 16 + l15] = acc[mi][ni][r];
            }
    } else {
#pragma unroll
        for (int mi = 0; mi < 4; ++mi)
#pragma unroll
            for (int r = 0; r < 4; ++r) {
                int mrow = m0 + wy * 64 + mi * 16 + lq * 4 + r;
#pragma unroll
                for (int ni = 0; ni < 4; ++ni)
                    antb[(size_t)mrow * 1024 + (n0 - 2048) + wx * 64 + ni * 16 + l15] =
                        bf16_rn(acc[mi][ni][r]);
            }
    }
}

// ---------------- small projections
__global__ void small_proj(const float* __restrict__ speaker_emb,
                           const float* __restrict__ bucket_emb,
                           const float* __restrict__ sp_W0,
                           float* __restrict__ spk_proj, float* __restrict__ bkt_proj)
{
    int r = blockIdx.x; // 0..11
    const float* e; const float* W; float* out;
    if (r < 2) { e = speaker_emb + r * 20; W = sp_W0 + (size_t)1536 * 1024; out = spk_proj + r * 1024; }
    else       { e = bucket_emb + (r - 2) * 20; W = sp_W0 + (size_t)1556 * 1024; out = bkt_proj + (r - 2) * 1024; }
    float ek[20];
#pragma unroll
    for (int k = 0; k < 20; ++k) ek[k] = e[k];
    for (int f = threadIdx.x; f < 1024; f += blockDim.x) {
        float s = 0.f;
#pragma unroll
        for (int k = 0; k < 20; ++k) s = fmaf(ek[k], W[(size_t)k * 1024 + f], s);
        out[f] = s;
    }
}

// ---------------- mention scores
__global__ __launch_bounds__(256) void mention_score(
    const float* __restrict__ H2, const float* __restrict__ ms_b0,
    const float* __restrict__ ms_W1, const float* __restrict__ ms_b1,
    float* __restrict__ ms)
{
    int m = blockIdx.x;
    float v = 0.f;
    for (int f = threadIdx.x; f < 1024; f += 256) {
        float h = H2[(size_t)m * 2048 + f] + ms_b0[f];
        v += fmaxf(h, 0.f) * ms_W1[f];
    }
#pragma unroll
    for (int o = 1; o < 64; o <<= 1) v += __shfl_xor(v, o);
    __shared__ float sm[4];
    if ((threadIdx.x & 63) == 0) sm[threadIdx.x >> 6] = v;
    __syncthreads();
    if (threadIdx.x == 0) ms[m] = sm[0] + sm[1] + sm[2] + sm[3] + ms_b1[0];
}

// ---------------- pair scorer v4c: block = (c-half, m), 512 thr = 8 waves, 2 blocks/CU.
// wave-tile = 32c x 64f, 4 passes; acc = 2 x f32x16 = 32 AGPR; ring a[2]+b[2][2].
// LESSON (R9/R10/R11 vs R6/R7): full `#pragma unroll` of the k-loop lets the
// scheduler hoist loads far past the ring window -> live-range blowup -> scratch
// spill (FETCH 200-260MB, ~1 TB/s of HBM on spill traffic). `#pragma unroll 2`
// keeps the ring distance-2 contract and stays within the (512,4) 128-reg budget.
__global__ __launch_bounds__(512, 4) void pair_mfma(
    const ushort* __restrict__ embb, const ushort* __restrict__ Wfrag3,
    const float* __restrict__ H2, const ushort* __restrict__ antb,
    const float* __restrict__ spk_proj, const float* __restrict__ bkt_proj,
    const float* __restrict__ sp_b0, const float* __restrict__ sp_W1,
    const int* __restrict__ speaker, float* __restrict__ slow)
{
    extern __shared__ ushort Afrag[];            // [ct:2][s:32][slot:64][8] = 32768 ushorts
    float* red = (float*)(Afrag + 32768);        // 4 pass * 8 wave * 32 = 1024 floats
    int* meta_ss = (int*)(red + 1024);           // 64
    int* meta_bk = meta_ss + 64;                 // 64
    const int ch = blockIdx.x;                   // c-half: 0 or 1
    const int m = blockIdx.y;
    const int tid = threadIdx.x;
    const int spk_m = speaker[m];

    // ---- build A fragments: A[c][k] = bf16(em[k]*ea[k]); fragment-major store
    {
        const int c = tid >> 3;                  // 0..63 block-local
        const int q = tid & 7;                   // k chunk q*64
        const int cg = ch * 64 + c;
        int a = m - 1 - cg; if (a < 0) a = 0;
        const ushort* ea = embb + (size_t)a * 512 + q * 64;
        const ushort* em = embb + (size_t)m * 512 + q * 64;
        const int ct = c >> 5, c31 = c & 31;
#pragma unroll
        for (int j0 = 0; j0 < 64; j0 += 8) {
            bf16x8 va = *(const bf16x8*)(ea + j0);
            bf16x8 vm = *(const bf16x8*)(em + j0);
            uint pr[4];
#pragma unroll
            for (int p = 0; p < 4; ++p) {
                float q0 = bf16_to_f((ushort)va[2 * p])     * bf16_to_f((ushort)vm[2 * p]);
                float q1 = bf16_to_f((ushort)va[2 * p + 1]) * bf16_to_f((ushort)vm[2 * p + 1]);
                pr[p] = __builtin_amdgcn_perm(__float_as_uint(q1), __float_as_uint(q0), 0x07060302u);
            }
            const int s = q * 4 + (j0 >> 4);
            const int h = (j0 >> 3) & 1;
            ((uint4*)Afrag)[(ct * 32 + s) * 64 + h * 32 + c31] = *(uint4*)pr;
        }
        if (tid < 64) {
            const int cc = tid, cgg = ch * 64 + cc;
            int aa = m - 1 - cgg; if (aa < 0) aa = 0;
            meta_ss[cc] = (speaker[aa] == spk_m) ? 1 : 0;
            int off = cgg + 1;
            int bk;
            if (off <= 4) bk = off;
            else { bk = 31 - __clz(off) + 3; if (bk > 9) bk = 9; }
            meta_bk[cc] = bk;
        }
    }
    __syncthreads();

    const int lane = tid & 63;
    const int wave = __builtin_amdgcn_readfirstlane(tid >> 6);   // 0..7
    const int wc = wave & 1;          // c-tile within block
    const int wf = wave >> 1;         // f-group 0..3
    const int l31 = lane & 31, k5 = lane >> 5;

    // A base: lane slot fixed; step s at immediate offset s*1024 B
    const ushort* ap = Afrag + ((size_t)wc * 2048 + lane) * 8;

    for (int pass = 0; pass < 4; ++pass) {
        const int chunk = pass * 4 + wf;         // 64-f chunk
        const ushort* P = Wfrag3 + (size_t)chunk * 32768 + (size_t)lane * 8;

        f32x16 acc0 = (f32x16)0.f, acc1 = (f32x16)0.f;
        bf16x8 a[2], b[2][2];

        a[0] = *(const bf16x8*)(ap);
        a[1] = *(const bf16x8*)(ap + 512);
        b[0][0] = *(const bf16x8*)(P);
        b[0][1] = *(const bf16x8*)(P + 512);
        b[1][0] = *(const bf16x8*)(P + 1024);
        b[1][1] = *(const bf16x8*)(P + 1536);
        P += 2048;

#pragma unroll 2
        for (int s = 0; s < 32; ++s) {
            const int cur = s & 1;
            acc0 = __builtin_amdgcn_mfma_f32_32x32x16_bf16(a[cur], b[cur][0], acc0, 0, 0, 0);
            acc1 = __builtin_amdgcn_mfma_f32_32x32x16_bf16(a[cur], b[cur][1], acc1, 0, 0, 0);
            // prefetch s+2 (s=30,31 wrap into valid-but-unused ws/LDS bytes)
            a[cur] = *(const bf16x8*)(ap + (s + 2) * 512);
            b[cur][0] = *(const bf16x8*)(P);
            b[cur][1] = *(const bf16x8*)(P + 512);
            P += 1024;
        }

        // ---- epilogue for this pass (f-chunk chunk*64..+63)
        const int fb = chunk * 64 + l31;
        float srcb[2], w1v[2], sp0v[2], sp1v[2];
#pragma unroll
        for (int t = 0; t < 2; ++t) {
            const int fcol = fb + t * 32;
            srcb[t] = H2[(size_t)m * 2048 + 1024 + fcol] + sp_b0[fcol];
            w1v[t]  = sp_W1[fcol];
            sp0v[t] = spk_proj[fcol];
            sp1v[t] = spk_proj[1024 + fcol];
        }
#pragma unroll
        for (int reg = 0; reg < 16; ++reg) {
            const int row = 4 * k5 + (reg & 3) + 8 * (reg >> 2);
            const int c = wc * 32 + row;
            const int cg = ch * 64 + c;
            int a2 = m - 1 - cg; if (a2 < 0) a2 = 0;
            const int ss2 = meta_ss[c];
            const int bk = meta_bk[c];
            const ushort* antp = antb + (size_t)a2 * 1024;
            const float* bkp = bkt_proj + (size_t)bk * 1024;
            float av2[2] = { acc0[reg], acc1[reg] };
            float s = 0.f;
#pragma unroll
            for (int t = 0; t < 2; ++t) {
                const int fcol = fb + t * 32;
                float pre = av2[t] + srcb[t] + bf16_to_f(antp[fcol])
                          + (ss2 ? sp1v[t] : sp0v[t]) + bkp[fcol];
                s += fmaxf(pre, 0.f) * w1v[t];
            }
            s += __shfl_xor(s, 1); s += __shfl_xor(s, 2); s += __shfl_xor(s, 4);
            s += __shfl_xor(s, 8); s += __shfl_xor(s, 16);
            if (l31 == 0) red[pass * 256 + wave * 32 + row] = s;
        }
    }
    __syncthreads();
    if (tid < 64) {
        const int c = tid, row = c & 31, wcc = c >> 5;
        float s = 0.f;
#pragma unroll
        for (int pass = 0; pass < 4; ++pass)
#pragma unroll
            for (int wff = 0; wff < 4; ++wff)
                s += red[pass * 256 + (wff * 2 + wcc) * 32 + row];
        slow[(size_t)m * 128 + ch * 64 + c] = s;
    }
}

// ---------------- softmax + per-mention loss
__device__ __forceinline__ float bsum2(float v, float* sm) {
#pragma unroll
    for (int o = 1; o < 64; o <<= 1) v += __shfl_xor(v, o);
    __syncthreads();
    if ((threadIdx.x & 63) == 0) sm[threadIdx.x >> 6] = v;
    __syncthreads();
    return sm[0] + sm[1];
}
__device__ __forceinline__ float bmax2(float v, float* sm) {
#pragma unroll
    for (int o = 1; o < 64; o <<= 1) v = fmaxf(v, __shfl_xor(v, o));
    __syncthreads();
    if ((threadIdx.x & 63) == 0) sm[threadIdx.x >> 6] = v;
    __syncthreads();
    return fmaxf(sm[0], sm[1]);
}

__global__ __launch_bounds__(128) void softmax_loss(
    const float* __restrict__ slow, const float* __restrict__ ms,
    const float* __restrict__ sp_b1, const int* __restrict__ cluster,
    float* __restrict__ out, float* __restrict__ loss_partial)
{
    const int m = blockIdx.x, c = threadIdx.x;
    __shared__ float sm[2];
    const int raw = m - 1 - c;
    const bool maskv = raw >= 0;
    const int a = maskv ? raw : 0;
    float score = slow[(size_t)m * 128 + c] + sp_b1[0] + ms[m] + ms[a];
    if (!maskv) score = -INFINITY;

    float mx = fmaxf(bmax2(score, sm), 0.f);
    float e = expf(score - mx);
    float e0 = expf(0.f - mx);
    float sum = bsum2(e, sm) + e0;
    float p = e / sum, p0 = e0 / sum;
    const float eps = 1e-6f;
    p  = fminf(fmaxf(p,  eps), 1.f - eps);
    p0 = fminf(fmaxf(p0, eps), 1.f - eps);
    float sum2 = bsum2(p, sm) + p0;
    p /= sum2; p0 /= sum2;
    out[(size_t)m * 129 + 1 + c] = p;
    if (c == 0) out[(size_t)m * 129] = p0;

    const int cid = cluster[m];
    const bool lbl = maskv && (cid > 0) && (cluster[a] == cid);
    float anyc = bsum2(lbl ? 1.f : 0.f, sm);
    float lsum = bsum2(lbl ? -logf(p) : 0.f, sm);
    if (c == 0) {
        if (anyc == 0.f) lsum += -logf(p0);
        loss_partial[m] = lsum;
    }
}

__global__ void loss_sum(const float* __restrict__ lp, float* __restrict__ out) {
    float v = 0.f;
    for (int i = threadIdx.x; i < 1024; i += 256) v += lp[i];
#pragma unroll
    for (int o = 1; o < 64; o <<= 1) v += __shfl_xor(v, o);
    __shared__ float sm[4];
    if ((threadIdx.x & 63) == 0) sm[threadIdx.x >> 6] = v;
    __syncthreads();
    if (threadIdx.x == 0) out[(size_t)1024 * 129] = sm[0] + sm[1] + sm[2] + sm[3];
}

extern "C" void kernel_launch(void* const* d_in, const int* in_sizes, int n_in,
                              void* d_out, int out_size, void* d_ws, size_t ws_size,
                              hipStream_t stream)
{
    const float* emb   = (const float*)d_in[0];
    const int*   clus  = (const int*)  d_in[1];
    const int*   spk   = (const int*)  d_in[2];
    const float* ms_W0 = (const float*)d_in[3];
    const float* ms_b0 = (const float*)d_in[4];
    const float* ms_W1 = (const float*)d_in[5];
    const float* ms_b1 = (const float*)d_in[6];
    const float* sp_W0 = (const float*)d_in[7];
    const float* sp_b0 = (const float*)d_in[8];
    const float* sp_W1 = (const float*)d_in[9];
    const float* sp_b1 = (const float*)d_in[10];
    const float* spke  = (const float*)d_in[11];
    const float* bkte  = (const float*)d_in[12];

    float* ws = (float*)d_ws;
    float*  H2       = ws;
    ushort* antb     = (ushort*)(ws + 2097152);
    float*  slow     = ws + 2621440;
    float*  spk_proj = ws + 2752512;
    float*  bkt_proj = ws + 2754560;
    float*  msc      = ws + 2764800;
    float*  lossp    = ws + 2765824;
    ushort* embb     = (ushort*)(ws + 2766848);
    ushort* Wall     = (ushort*)(ws + 3028992);
    ushort* Wfrag3   = Wall + (size_t)3072 * 512;   // 1MB tail of Wall region
    float* out = (float*)d_out;

    const int pair_lds = 32768 * 2 + 1024 * 4 + 128 * 4;   // Afrag + red + meta = 70144 B

    static bool attr_set = false;
    if (!attr_set) {
        hipFuncSetAttribute((const void*)pair_mfma,
                            hipFuncAttributeMaxDynamicSharedMemorySize,
                            pair_lds);
        attr_set = true;
    }

    hipLaunchKernelGGL(prep_emb, dim3(1024), dim3(256), 0, stream, emb, embb);
    hipLaunchKernelGGL(prep_wall, dim3(8, 48), dim3(256), 0, stream, ms_W0, sp_W0, Wall);
    hipLaunchKernelGGL(prep_wfrag3, dim3(16, 32), dim3(128), 0, stream, sp_W0, Wfrag3);
    hipLaunchKernelGGL(gemm_h_mfma, dim3(24, 8), dim3(256), 0, stream, embb, Wall, H2, antb);
    hipLaunchKernelGGL(small_proj, dim3(12), dim3(256), 0, stream, spke, bkte, sp_W0, spk_proj, bkt_proj);
    hipLaunchKernelGGL(mention_score, dim3(1024), dim3(256), 0, stream, H2, ms_b0, ms_W1, ms_b1, msc);
    hipLaunchKernelGGL(pair_mfma, dim3(2, 1024), dim3(512), pair_lds, stream,
                       embb, Wfrag3, H2, antb, spk_proj, bkt_proj, sp_b0, sp_W1, spk, slow);
    hipLaunchKernelGGL(softmax_loss, dim3(1024), dim3(128), 0, stream,
                       slow, msc, sp_b1, clus, out, lossp);
    hipLaunchKernelGGL(loss_sum, dim3(1), dim3(256), 0, stream, lossp, out);
}